// Round 1
// baseline (690.895 us; speedup 1.0000x reference)
//
#include <hip/hip_runtime.h>
#include <hip/hip_bf16.h>
#include <math.h>

#define BT 16384
#define DDIM 1024
#define NEXP 16
#define HDIM 2048
#define CAP 1280
#define APITCH 72

typedef __bf16 bf16x8 __attribute__((ext_vector_type(8)));
typedef float f32x4 __attribute__((ext_vector_type(4)));

__device__ __forceinline__ unsigned short f2bf(float f) {
  unsigned u = __float_as_uint(f);
  u += 0x7FFFu + ((u >> 16) & 1u);
  return (unsigned short)(u >> 16);
}

__global__ void zero_meta_kernel(int* p) {
  int i = blockIdx.x * 256 + threadIdx.x;
  if (i < 32 + BT) p[i] = 0;
}

// ---------------- gate: logits = x @ Wg, double accum; argmax + top1 prob ----
__global__ __launch_bounds__(256) void gate_kernel(
    const float* __restrict__ x, const float* __restrict__ Wg,
    int* __restrict__ e, float* __restrict__ v, int* __restrict__ counts) {
  __shared__ float wgt[NEXP][DDIM];  // Wg transposed, 64KB
  int tid = threadIdx.x;
  for (int i = tid; i < DDIM * NEXP / 4; i += 256) {
    int idx = i * 4;
    int d = idx >> 4, n = idx & 15;
    float4 w = *(const float4*)(Wg + idx);
    wgt[n + 0][d] = w.x; wgt[n + 1][d] = w.y;
    wgt[n + 2][d] = w.z; wgt[n + 3][d] = w.w;
  }
  __syncthreads();
  int lane = tid & 63;
  int gw = blockIdx.x * 4 + (tid >> 6);  // global wave id, 4096 waves
  for (int t = gw; t < BT; t += 4096) {
    double acc[NEXP];
#pragma unroll
    for (int n = 0; n < NEXP; ++n) acc[n] = 0.0;
    for (int i = 0; i < 16; ++i) {
      int d = i * 64 + lane;
      float xv = x[(size_t)t * DDIM + d];
#pragma unroll
      for (int n = 0; n < NEXP; ++n) acc[n] += (double)xv * (double)wgt[n][d];
    }
#pragma unroll
    for (int n = 0; n < NEXP; ++n) {
      double a = acc[n];
#pragma unroll
      for (int off = 32; off > 0; off >>= 1) a += __shfl_xor(a, off);
      acc[n] = a;
    }
    if (lane == 0) {
      double mx = acc[0]; int bi = 0;
#pragma unroll
      for (int n = 1; n < NEXP; ++n) if (acc[n] > mx) { mx = acc[n]; bi = n; }
      double s = 0.0;
#pragma unroll
      for (int n = 0; n < NEXP; ++n) s += exp(acc[n] - mx);
      e[t] = bi;
      v[t] = (float)(1.0 / s);
      atomicAdd(&counts[bi], 1);
    }
  }
}

// ---------------- select: per-expert token set under capacity ---------------
__global__ void select_kernel(const int* __restrict__ e, const float* __restrict__ v,
                              const int* __restrict__ counts, int* __restrict__ m_sel,
                              int* __restrict__ lists, int* __restrict__ flags) {
  int n = blockIdx.x;
  int tid = threadIdx.x;
  int cnt = counts[n];
  if (cnt <= CAP) {
    for (int t = tid; t < BT; t += 256) {
      if (e[t] == n) {
        int p = atomicAdd(&m_sel[n], 1);
        lists[n * CAP + p] = t;
        flags[t] = 1;
      }
    }
  } else {
    // exact top-CAP by value (desc), ties -> lowest index (top_k semantics).
    __shared__ int scnt;
    unsigned lo = 0u, hi = 0x7F800000u;  // v in (0,1]: positive floats, uint order == float order
    while (hi - lo > 1u) {
      unsigned mid = lo + ((hi - lo) >> 1);
      if (tid == 0) scnt = 0;
      __syncthreads();
      int c = 0;
      for (int t = tid; t < BT; t += 256)
        if (e[t] == n && __float_as_uint(v[t]) >= mid) c++;
      atomicAdd(&scnt, c);
      __syncthreads();
      int tot = scnt;
      __syncthreads();
      if (tot >= CAP) lo = mid; else hi = mid;
    }
    for (int t = tid; t < BT; t += 256) {
      if (e[t] == n && __float_as_uint(v[t]) > lo) {
        int p = atomicAdd(&m_sel[n], 1);
        lists[n * CAP + p] = t;
        flags[t] = 1;
      }
    }
    __syncthreads();
    if (tid == 0) {
      int p = atomicAdd(&m_sel[n], 0);
      for (int t = 0; t < BT && p < CAP; ++t) {
        if (e[t] == n && __float_as_uint(v[t]) == lo) {
          lists[n * CAP + p] = t; flags[t] = 1; ++p;
        }
      }
      m_sel[n] = p;
    }
  }
}

// ---------------- FFN1: H = gelu(gather(x) @ W1 + b1), bf16 out -------------
__global__ __launch_bounds__(256) void ffn1_kernel(
    const float* __restrict__ x, const float* __restrict__ W1, const float* __restrict__ b1,
    const int* __restrict__ m_sel, const int* __restrict__ lists,
    unsigned short* __restrict__ H) {
  __shared__ unsigned short Al[128 * APITCH];  // [row][k] bf16, pitch 72
  __shared__ unsigned short Bl[128 * APITCH];  // [h][k] bf16 (transposed), pitch 72
  __shared__ int rows[128];
  int n = blockIdx.z, mt = blockIdx.y, ht = blockIdx.x;
  int M = m_sel[n];
  if (mt * 128 >= M) return;
  int tid = threadIdx.x;
  if (tid < 128) {
    int s = mt * 128 + tid;
    rows[tid] = lists[n * CAP + (s < M ? s : 0)];
  }
  __syncthreads();
  f32x4 acc[4][4] = {};
  int lane = tid & 63;
  int wid = tid >> 6;
  int wr = (wid >> 1) * 64, wc = (wid & 1) * 64;
  int ar = tid >> 4, ac = (tid & 15) * 4;       // A staging
  int bh = tid & 127, bk8 = (tid >> 7) * 8;     // B staging
  const size_t w1base = (size_t)n * DDIM * HDIM + (size_t)ht * 128;

  for (int kt = 0; kt < DDIM / 64; ++kt) {
#pragma unroll
    for (int i = 0; i < 8; ++i) {
      int r = ar + i * 16;
      float4 xv = *(const float4*)(x + (size_t)rows[r] * DDIM + kt * 64 + ac);
      unsigned plo = (unsigned)f2bf(xv.x) | ((unsigned)f2bf(xv.y) << 16);
      unsigned phi = (unsigned)f2bf(xv.z) | ((unsigned)f2bf(xv.w) << 16);
      *(uint2*)(&Al[r * APITCH + ac]) = make_uint2(plo, phi);
    }
#pragma unroll
    for (int i = 0; i < 4; ++i) {
      int k0 = bk8 + i * 16;
      const float* wp = W1 + w1base + (size_t)(kt * 64 + k0) * HDIM + bh;
      float f0 = wp[0];
      float f1 = wp[HDIM];
      float f2 = wp[2 * HDIM];
      float f3 = wp[3 * HDIM];
      float f4 = wp[4 * HDIM];
      float f5 = wp[5 * HDIM];
      float f6 = wp[6 * HDIM];
      float f7 = wp[7 * HDIM];
      uint4 pk;
      pk.x = (unsigned)f2bf(f0) | ((unsigned)f2bf(f1) << 16);
      pk.y = (unsigned)f2bf(f2) | ((unsigned)f2bf(f3) << 16);
      pk.z = (unsigned)f2bf(f4) | ((unsigned)f2bf(f5) << 16);
      pk.w = (unsigned)f2bf(f6) | ((unsigned)f2bf(f7) << 16);
      *(uint4*)(&Bl[bh * APITCH + k0]) = pk;
    }
    __syncthreads();
#pragma unroll
    for (int kk = 0; kk < 2; ++kk) {
      bf16x8 af[4], bfr[4];
#pragma unroll
      for (int mi = 0; mi < 4; ++mi)
        af[mi] = *(const bf16x8*)(&Al[(wr + mi * 16 + (lane & 15)) * APITCH + kk * 32 + (lane >> 4) * 8]);
#pragma unroll
      for (int ni = 0; ni < 4; ++ni)
        bfr[ni] = *(const bf16x8*)(&Bl[(wc + ni * 16 + (lane & 15)) * APITCH + kk * 32 + (lane >> 4) * 8]);
#pragma unroll
      for (int mi = 0; mi < 4; ++mi)
#pragma unroll
        for (int ni = 0; ni < 4; ++ni)
          acc[mi][ni] = __builtin_amdgcn_mfma_f32_16x16x32_bf16(af[mi], bfr[ni], acc[mi][ni], 0, 0, 0);
    }
    __syncthreads();
  }
  int rq = (lane >> 4) * 4;
#pragma unroll
  for (int ni = 0; ni < 4; ++ni) {
    int h = ht * 128 + wc + ni * 16 + (lane & 15);
    float bias = b1[n * HDIM + h];
#pragma unroll
    for (int mi = 0; mi < 4; ++mi) {
#pragma unroll
      for (int q = 0; q < 4; ++q) {
        int lr = wr + mi * 16 + rq + q;
        float val = acc[mi][ni][q] + bias;
        float g = 0.5f * val * (1.0f + tanhf(0.7978845608028654f * (val + 0.044715f * val * val * val)));
        H[((size_t)n * CAP + mt * 128 + lr) * HDIM + h] = f2bf(g);
      }
    }
  }
}

// ---------------- FFN2: out = H @ W2 + b2, scatter to tokens ----------------
__global__ __launch_bounds__(256) void ffn2_kernel(
    const unsigned short* __restrict__ H, const float* __restrict__ W2, const float* __restrict__ b2,
    const int* __restrict__ m_sel, const int* __restrict__ lists,
    float* __restrict__ out) {
  __shared__ unsigned short Al[128 * APITCH];
  __shared__ unsigned short Bl[128 * APITCH];
  __shared__ int rows[128];
  int n = blockIdx.z, mt = blockIdx.y, dt = blockIdx.x;
  int M = m_sel[n];
  if (mt * 128 >= M) return;
  int tid = threadIdx.x;
  if (tid < 128) {
    int s = mt * 128 + tid;
    rows[tid] = lists[n * CAP + (s < M ? s : 0)];
  }
  __syncthreads();
  f32x4 acc[4][4] = {};
  int lane = tid & 63;
  int wid = tid >> 6;
  int wr = (wid >> 1) * 64, wc = (wid & 1) * 64;
  int ar2 = tid >> 1, ak8 = (tid & 1) * 8;
  int bh = tid & 127, bk8 = (tid >> 7) * 8;
  const size_t hbase = ((size_t)n * CAP + (size_t)mt * 128) * HDIM;
  const size_t w2base = (size_t)n * HDIM * DDIM + (size_t)dt * 128;

  for (int kt = 0; kt < HDIM / 64; ++kt) {
#pragma unroll
    for (int i = 0; i < 4; ++i) {
      int k0 = ak8 + i * 16;
      uint4 hv = *(const uint4*)(H + hbase + (size_t)ar2 * HDIM + kt * 64 + k0);
      *(uint4*)(&Al[ar2 * APITCH + k0]) = hv;
    }
#pragma unroll
    for (int i = 0; i < 4; ++i) {
      int k0 = bk8 + i * 16;
      const float* wp = W2 + w2base + (size_t)(kt * 64 + k0) * DDIM + bh;
      float f0 = wp[0];
      float f1 = wp[DDIM];
      float f2 = wp[2 * DDIM];
      float f3 = wp[3 * DDIM];
      float f4 = wp[4 * DDIM];
      float f5 = wp[5 * DDIM];
      float f6 = wp[6 * DDIM];
      float f7 = wp[7 * DDIM];
      uint4 pk;
      pk.x = (unsigned)f2bf(f0) | ((unsigned)f2bf(f1) << 16);
      pk.y = (unsigned)f2bf(f2) | ((unsigned)f2bf(f3) << 16);
      pk.z = (unsigned)f2bf(f4) | ((unsigned)f2bf(f5) << 16);
      pk.w = (unsigned)f2bf(f6) | ((unsigned)f2bf(f7) << 16);
      *(uint4*)(&Bl[bh * APITCH + k0]) = pk;
    }
    __syncthreads();
#pragma unroll
    for (int kk = 0; kk < 2; ++kk) {
      bf16x8 af[4], bfr[4];
#pragma unroll
      for (int mi = 0; mi < 4; ++mi)
        af[mi] = *(const bf16x8*)(&Al[(wr + mi * 16 + (lane & 15)) * APITCH + kk * 32 + (lane >> 4) * 8]);
#pragma unroll
      for (int ni = 0; ni < 4; ++ni)
        bfr[ni] = *(const bf16x8*)(&Bl[(wc + ni * 16 + (lane & 15)) * APITCH + kk * 32 + (lane >> 4) * 8]);
#pragma unroll
      for (int mi = 0; mi < 4; ++mi)
#pragma unroll
        for (int ni = 0; ni < 4; ++ni)
          acc[mi][ni] = __builtin_amdgcn_mfma_f32_16x16x32_bf16(af[mi], bfr[ni], acc[mi][ni], 0, 0, 0);
    }
    __syncthreads();
  }
  int rq = (lane >> 4) * 4;
#pragma unroll
  for (int mi = 0; mi < 4; ++mi) {
#pragma unroll
    for (int q = 0; q < 4; ++q) {
      int lr = wr + mi * 16 + rq + q;
      int s = mt * 128 + lr;
      if (s < M) {
        int tok = rows[lr];
#pragma unroll
        for (int ni = 0; ni < 4; ++ni) {
          int dcol = dt * 128 + wc + ni * 16 + (lane & 15);
          out[(size_t)tok * DDIM + dcol] = acc[mi][ni][q] + b2[n * DDIM + dcol];
        }
      }
    }
  }
}

// ---------------- passthrough for unselected tokens -------------------------
__global__ void passthrough_kernel(const float* __restrict__ x, const int* __restrict__ flags,
                                   float* __restrict__ out) {
  int t = blockIdx.x;
  if (flags[t]) return;
  const float4* s = (const float4*)(x + (size_t)t * DDIM);
  float4* d = (float4*)(out + (size_t)t * DDIM);
  d[threadIdx.x] = s[threadIdx.x];
}

extern "C" void kernel_launch(void* const* d_in, const int* in_sizes, int n_in,
                              void* d_out, int out_size, void* d_ws, size_t ws_size,
                              hipStream_t stream) {
  const float* x  = (const float*)d_in[0];
  const float* Wg = (const float*)d_in[1];
  const float* W1 = (const float*)d_in[2];
  const float* b1 = (const float*)d_in[3];
  const float* W2 = (const float*)d_in[4];
  const float* b2 = (const float*)d_in[5];
  float* out = (float*)d_out;
  char* ws = (char*)d_ws;
  int* counts = (int*)ws;                     // 16 ints
  int* m_sel  = (int*)(ws + 64);              // 16 ints
  int* flags  = (int*)(ws + 128);             // BT ints
  int* e      = (int*)(ws + 128 + 4 * BT);    // BT ints
  float* v    = (float*)(ws + 128 + 8 * BT);  // BT floats
  int* lists  = (int*)(ws + 128 + 12 * BT);   // NEXP*CAP ints
  unsigned short* H = (unsigned short*)(ws + (1 << 20));  // [NEXP][CAP][HDIM] bf16 ~ 84MB

  zero_meta_kernel<<<(32 + BT + 255) / 256, 256, 0, stream>>>(counts);
  gate_kernel<<<1024, 256, 0, stream>>>(x, Wg, e, v, counts);
  select_kernel<<<NEXP, 256, 0, stream>>>(e, v, counts, m_sel, lists, flags);
  ffn1_kernel<<<dim3(HDIM / 128, CAP / 128, NEXP), 256, 0, stream>>>(x, W1, b1, m_sel, lists, H);
  ffn2_kernel<<<dim3(DDIM / 128, CAP / 128, NEXP), 256, 0, stream>>>(H, W2, b2, m_sel, lists, out);
  passthrough_kernel<<<BT, 256, 0, stream>>>(x, flags, out);
}